// Round 6
// baseline (320.919 us; speedup 1.0000x reference)
//
#include <hip/hip_runtime.h>
#include <hip/hip_bf16.h>

typedef __hip_bfloat16 bf16;
typedef __attribute__((ext_vector_type(8))) short short8;
typedef __attribute__((ext_vector_type(4))) float float4v;

#define Hd 256
#define Wd 256
#define HW 65536
#define CO 64

// ---------------------------------------------------------------------------
// K1: style MLP + modulated/demodulated weights. One block per (o, s).
// wA layout: [s][kc(18)][o(64)][32], k = tap*64 + i (tap-major).
// ---------------------------------------------------------------------------
__global__ __launch_bounds__(64) void k1_style(
    const float* __restrict__ vec, const float* __restrict__ w1,
    const float* __restrict__ w2, const float* __restrict__ wconv,
    bf16* __restrict__ wA)
{
    int o = blockIdx.x;      // 0..63
    int s = blockIdx.y;      // 0..7
    int i = threadIdx.x;     // lane = input channel

    float sv[4];
#pragma unroll
    for (int q = 0; q < 4; ++q) sv[q] = vec[s * 256 + q * 64 + i];

    float hid[16];
#pragma unroll
    for (int j = 0; j < 16; ++j) {
        float p = 0.f;
#pragma unroll
        for (int q = 0; q < 4; ++q) p += sv[q] * w1[j * 256 + q * 64 + i];
#pragma unroll
        for (int off = 32; off >= 1; off >>= 1) p += __shfl_xor(p, off, 64);
        hid[j] = p > 0.f ? p : 0.1f * p;   // LeakyReLU(0.1)
    }
    float sty = 0.f;
#pragma unroll
    for (int j = 0; j < 16; ++j) sty += w2[i * 16 + j] * hid[j];
    float msty = sty + 1.0f;               // per input-channel i

    float wrow[9];
#pragma unroll
    for (int tt = 0; tt < 9; ++tt) wrow[tt] = wconv[(o * 64 + i) * 9 + tt] * msty;
    float ss = 0.f;
#pragma unroll
    for (int tt = 0; tt < 9; ++tt) ss += wrow[tt] * wrow[tt];
#pragma unroll
    for (int off = 32; off >= 1; off >>= 1) ss += __shfl_xor(ss, off, 64);
    float d = rsqrtf(ss + 1e-8f);

    bf16* wAs = wA + s * (18 * 64 * 32);
#pragma unroll
    for (int tt = 0; tt < 9; ++tt) {
        int k = tt * 64 + i;
        wAs[(k >> 5) * 2048 + o * 32 + (k & 31)] = (bf16)(wrow[tt] * d);
    }
}

// ---------------------------------------------------------------------------
// K2: ChanNorm + layout transform  x[s][c][h][w] fp32  ->  nx[s][h][w][c] bf16
// plus per-pixel stats sms[s][h][w] = {mean, std} for K3's residual
// reconstruction. Block = (h, s), 256 threads, no LDS, no barriers.
//
// Thread micro-tile: 4 channels (cg = t&15 -> c = cg*4..+3) x 4 pixels
// (pg = t>>4, 4 passes of 64 px). Loads: float4 along W, fully coalesced.
// Stats: per-pixel sum over 64 ch = this thread's 4-ch partial reduced
// across the 16 lanes sharing pg via __shfl_xor (bits 0..3 of lane id).
// Stores: per pixel, 4 bf16 (this thread's channels) as one 8 B word;
// 16 lanes with consecutive cg cover the pixel's 128 B contiguously.
// ---------------------------------------------------------------------------
__global__ __launch_bounds__(256) void k2_norm(
    const float* __restrict__ x, const float* __restrict__ gg,
    const float* __restrict__ bb, bf16* __restrict__ nx,
    float2* __restrict__ sms)
{
    int h = blockIdx.x, s = blockIdx.y;
    int t = threadIdx.x;
    int cg = t & 15;          // channel group: channels cg*4 .. cg*4+3
    int pg = t >> 4;          // pixel group of 4 within each 64-px pass
    float4 g4 = *(const float4*)&gg[cg * 4];
    float4 b4 = *(const float4*)&bb[cg * 4];
    const float* xrow = x + (size_t)s * ((size_t)CO * HW) + (size_t)h * Wd;
    bf16*   nxrow  = nx  + ((size_t)s * HW + (size_t)h * Wd) * CO;
    float2* smsrow = sms +  (size_t)s * HW + (size_t)h * Wd;

#pragma unroll 1
    for (int it = 0; it < 4; ++it) {
        int px = it * 64 + pg * 4;
        float4 v[4];
#pragma unroll
        for (int cc = 0; cc < 4; ++cc)
            v[cc] = *(const float4*)&xrow[(size_t)(cg * 4 + cc) * HW + px];

        float s1[4], s2[4];
#pragma unroll
        for (int pi = 0; pi < 4; ++pi) {
            float a0 = (&v[0].x)[pi], a1 = (&v[1].x)[pi];
            float a2 = (&v[2].x)[pi], a3 = (&v[3].x)[pi];
            s1[pi] = (a0 + a1) + (a2 + a3);
            s2[pi] = (a0 * a0 + a1 * a1) + (a2 * a2 + a3 * a3);
        }
#pragma unroll
        for (int off = 1; off <= 8; off <<= 1)
#pragma unroll
            for (int pi = 0; pi < 4; ++pi) {
                s1[pi] += __shfl_xor(s1[pi], off, 64);
                s2[pi] += __shfl_xor(s2[pi], off, 64);
            }
        float mean[4], rstd[4], stdv[4];
#pragma unroll
        for (int pi = 0; pi < 4; ++pi) {
            mean[pi] = s1[pi] * (1.f / 64);
            float var = s2[pi] * (1.f / 64) - mean[pi] * mean[pi];
            rstd[pi] = rsqrtf(var + 1e-5f);
            stdv[pi] = sqrtf(var + 1e-5f);
        }
        if (cg == 0) {
#pragma unroll
            for (int pi = 0; pi < 4; ++pi)
                smsrow[px + pi] = make_float2(mean[pi], stdv[pi]);
        }
#pragma unroll
        for (int pi = 0; pi < 4; ++pi) {
            union { uint2 u; bf16 hh[4]; } o;
#pragma unroll
            for (int cc = 0; cc < 4; ++cc) {
                float f  = (&v[cc].x)[pi];
                float gv = (&g4.x)[cc], bv = (&b4.x)[cc];
                o.hh[cc] = (bf16)((f - mean[pi]) * rstd[pi] * gv + bv);
            }
            *(uint2*)&nxrow[(size_t)(px + pi) * CO + cg * 4] = o.u;
        }
    }
}

// ---------------------------------------------------------------------------
// K3: implicit-GEMM 3x3 conv + residual, consuming channel-last nx.
// Block = (s, 8 output rows, 32-px strip). Halo tile 10 rows x 34 px.
// P1 stage = PURE COPY: 16 x uint4 per thread from nx (vectorized,
// contiguous 128 B per site) -> LDS tile [row][c8][wl][8]. No norm, no
// stats, ONE barrier. afrag (18x2, resident) + per-row sms prefetched
// before the barrier so their latency hides under the LDS drain.
// P3: row-outer (unroll 2), kc-inner; each B ds_read feeds 2 MFMAs.
// Residual: x = (nx - b[o]) / g[o] * std + mean from LDS tile + sms.
// ---------------------------------------------------------------------------
#define PXB 32
#define ROWS 8
#define TR 10
#define WL 34
#define NSITES (TR * WL)          // 340
#define ROW_ELEMS (8 * WL * 8)    // 2176 elems = 4352 B; 10 rows = 43520 B

union U4 { uint4 u; bf16 h[8]; short8 s8; };

__global__ __launch_bounds__(256) void k3_conv(
    const bf16* __restrict__ nx, const float2* __restrict__ sms,
    const float* __restrict__ gg, const float* __restrict__ bb,
    const bf16* __restrict__ wA, float* __restrict__ out)
{
    int w0 = blockIdx.x * PXB;   // 0..7 -> 0..224
    int h0 = blockIdx.y * ROWS;  // 0..31 -> 0..248
    int s  = blockIdx.z;
    int t  = threadIdx.x;
    __shared__ __align__(16) bf16 tile[TR * ROW_ELEMS];
    __shared__ float2 sbi[64];           // {b[o], 1/g[o]} for reconstruction
    if (t < 64) sbi[t] = make_float2(bb[t], 1.0f / gg[t]);

    // ---- P1: copy-stage tile from channel-last nx ----
    int p0 = t, p1 = t + 256;
    bool live1 = (p1 < NSITES);          // threads 0..83 own a second site
    int dr0 = p0 / WL, wl0 = p0 - dr0 * WL;
    int dr1 = live1 ? (p1 / WL) : 0;
    int wl1 = live1 ? (p1 - dr1 * WL) : 0;
    int grow0 = h0 + dr0 - 1, wab0 = w0 + wl0 - 1;
    int grow1 = h0 + dr1 - 1, wab1 = w0 + wl1 - 1;
    bool ok0 = (grow0 >= 0 && grow0 < Hd && wab0 >= 0 && wab0 < Wd);
    bool ok1 = live1 && (grow1 >= 0 && grow1 < Hd && wab1 >= 0 && wab1 < Wd);
    const bf16* np0 = nx + ((size_t)s * HW + (size_t)grow0 * Wd + wab0) * CO;
    const bf16* np1 = nx + ((size_t)s * HW + (size_t)grow1 * Wd + wab1) * CO;
    bf16* dst0 = &tile[dr0 * ROW_ELEMS + wl0 * 8];
    bf16* dst1 = &tile[dr1 * ROW_ELEMS + wl1 * 8];
    uint4 z = make_uint4(0u, 0u, 0u, 0u);
#pragma unroll
    for (int c8 = 0; c8 < 8; ++c8) {
        uint4 a = ok0 ? *(const uint4*)&np0[c8 * 8] : z;
        *(uint4*)&dst0[c8 * (WL * 8)] = a;
    }
    if (live1) {
#pragma unroll
        for (int c8 = 0; c8 < 8; ++c8) {
            uint4 a = ok1 ? *(const uint4*)&np1[c8 * 8] : z;
            *(uint4*)&dst1[c8 * (WL * 8)] = a;
        }
    }

    int wave = t >> 6, lane = t & 63;
    int mi = wave & 1, ni = wave >> 1;   // wave: o in [mi*32,+32), px in [ni*16,+16)
    int col = lane & 15, quad = lane >> 4;

    // ---- prefetch A-frags + per-row sms; latency hides under LDS drain ----
    const bf16* wAs = wA + s * (18 * 64 * 32);
    short8 afrag[18][2];
#pragma unroll
    for (int kc = 0; kc < 18; ++kc)
#pragma unroll
        for (int mt = 0; mt < 2; ++mt) {
            U4 a;
            a.u = *(const uint4*)&wAs[kc * 2048 + (mi * 32 + mt * 16 + col) * 32 + quad * 8];
            afrag[kc][mt] = a.s8;
        }
    int wpx = w0 + ni * 16 + col;
    float2 msr[ROWS];
#pragma unroll
    for (int r = 0; r < ROWS; ++r)
        msr[r] = sms[(size_t)s * HW + (size_t)(h0 + r) * Wd + wpx];

    __syncthreads();   // the ONLY barrier

    // ---- P3: compute, row-outer, kc-inner; afrag resident ----
    int wl_i = ni * 16 + col + 1;
#pragma unroll 2
    for (int r = 0; r < ROWS; ++r) {
        float4v acc[2];
        acc[0] = (float4v)0.f; acc[1] = (float4v)0.f;
#pragma unroll
        for (int kc = 0; kc < 18; ++kc) {
            int tap = kc >> 1;
            int kh = tap / 3, kw = tap - kh * 3;
            int ch8 = (kc & 1) * 4 + quad;
            U4 b;
            b.u = *(const uint4*)&tile[(r + kh) * ROW_ELEMS + (ch8 * WL + ni * 16 + col + kw) * 8];
            acc[0] = __builtin_amdgcn_mfma_f32_16x16x32_bf16(afrag[kc][0], b.s8, acc[0], 0, 0, 0);
            acc[1] = __builtin_amdgcn_mfma_f32_16x16x32_bf16(afrag[kc][1], b.s8, acc[1], 0, 0, 0);
        }
        // epilogue: residual reconstructed from LDS tile + prefetched stats
        int grow = h0 + r;
        float2 ms = msr[r];
#pragma unroll
        for (int mt = 0; mt < 2; ++mt) {
#pragma unroll
            for (int rr = 0; rr < 4; ++rr) {
                int o = mi * 32 + mt * 16 + quad * 4 + rr;
                float nxf = __bfloat162float(
                    tile[(r + 1) * ROW_ELEMS + ((o >> 3) * WL + wl_i) * 8 + (o & 7)]);
                float2 bi = sbi[o];
                float xrec = (nxf - bi.x) * bi.y * ms.y + ms.x;
                size_t idx = (size_t)(s * CO + o) * HW + (size_t)grow * Wd + wpx;
                out[idx] = acc[mt][rr] + xrec;
            }
        }
    }
}

extern "C" void kernel_launch(void* const* d_in, const int* in_sizes, int n_in,
                              void* d_out, int out_size, void* d_ws, size_t ws_size,
                              hipStream_t stream)
{
    const float* x     = (const float*)d_in[0];
    const float* vec   = (const float*)d_in[1];
    const float* g     = (const float*)d_in[2];
    const float* bb    = (const float*)d_in[3];
    const float* w1    = (const float*)d_in[4];
    const float* w2    = (const float*)d_in[5];
    const float* wconv = (const float*)d_in[6];
    float* out = (float*)d_out;

    // workspace layout (ws_size >= 80 MB confirmed by R5 probe):
    //   [0, 576K)      wA   : 8*18*64*32 bf16
    //   [1M, 65M)      nx   : 8*65536*64 bf16 channel-last = 64 MB
    //   [65M, 69M)     sms  : 8*65536 float2 = 4 MB
    char* wsb = (char*)d_ws;
    bf16*   wA  = (bf16*)wsb;
    bf16*   nx  = (bf16*)(wsb + ((size_t)1 << 20));
    float2* sms = (float2*)(wsb + ((size_t)65 << 20));

    k1_style<<<dim3(64, 8), 64, 0, stream>>>(vec, w1, w2, wconv, wA);
    k2_norm<<<dim3(256, 8), 256, 0, stream>>>(x, g, bb, nx, sms);
    k3_conv<<<dim3(8, 32, 8), 256, 0, stream>>>(nx, sms, g, bb, wA, out);
}